// Round 1
// baseline (497.295 us; speedup 1.0000x reference)
//
#include <hip/hip_runtime.h>

#define T_TOK 65536
#define BATCH 64
#define XDIM  512
#define HDIM  512
#define YDIM  2560

#define TM 128
#define TN 128
#define BK 64
#define LDS_STRIDE 72   // 64 + 8 pad: row stride 144 B -> 4-bank shift/row, 2-way = free

typedef float  f32x4  __attribute__((ext_vector_type(4)));
typedef __bf16 bf16x8 __attribute__((ext_vector_type(8)));

__device__ __forceinline__ unsigned short f2bf(float f) {
    unsigned int u = __float_as_uint(f);
    return (unsigned short)((u + 0x7FFFu + ((u >> 16) & 1u)) >> 16);  // RNE
}

__device__ __forceinline__ int lower_bound_seg(const int* __restrict__ s, int n, int v) {
    int lo = 0, hi = n;
    while (lo < hi) { int mid = (lo + hi) >> 1; if (s[mid] < v) lo = mid + 1; else hi = mid; }
    return lo;
}

// ---------------- weight transpose + bf16 convert: dst[n*512+k] = bf16(src[(k)*512+n])
__global__ __launch_bounds__(256) void transpose_to_bf16(const float* __restrict__ src,
                                                         unsigned short* __restrict__ dst) {
    int idx = blockIdx.x * 256 + threadIdx.x;       // 512*512 total
    int nn = idx >> 9, kk = idx & 511;
    dst[idx] = f2bf(src[(size_t)kk * 512 + nn]);
}

// ---------------- seg_bias[b][n] = sum_k io[b*2560+k] * W1[(512+k)*512+n]  (fp32, k-split x4, atomic)
__global__ __launch_bounds__(512) void segbias_kernel(const float* __restrict__ io,
                                                      const float* __restrict__ w1,
                                                      float* __restrict__ segbias) {
    const int s = blockIdx.x;       // 0..3 k-split
    const int b = blockIdx.y;       // 0..63
    const int t = threadIdx.x;      // 0..511 = n
    __shared__ float sio[640];
    const int k0 = s * 640;
    for (int i = t; i < 640; i += 512) sio[i] = io[b * YDIM + k0 + i];
    __syncthreads();
    float acc = 0.f;
    #pragma unroll 4
    for (int k = 0; k < 640; k++)
        acc += sio[k] * w1[(size_t)(512 + k0 + k) * 512 + t];
    atomicAdd(&segbias[b * HDIM + t], acc);
}

// ---------------- GEMM1: h1 = relu(ps @ W1u + segbias[seg] + b1), bf16 out
__global__ __launch_bounds__(256) void gemm1_kernel(const float* __restrict__ ps,
                                                    const unsigned short* __restrict__ w1t,
                                                    const float* __restrict__ segbias,
                                                    const float* __restrict__ b1,
                                                    const int* __restrict__ segids,
                                                    unsigned short* __restrict__ h1) {
    __shared__ unsigned short shA[TM * LDS_STRIDE];
    __shared__ unsigned short shB[TN * LDS_STRIDE];

    const int bid = blockIdx.x;
    const int m0 = (bid >> 2) * TM;
    const int n0 = (bid & 3) * TN;
    const int t = threadIdx.x;
    const int w = t >> 6, L = t & 63;
    const int mbase = (w >> 1) * 64, nbase = (w & 1) * 64;
    const int lrow = L & 15, lq = L >> 4;

    f32x4 acc[4][4] = {};

    for (int kt = 0; kt < HDIM; kt += BK) {
        #pragma unroll
        for (int i = 0; i < 8; i++) {               // A: 128x64 fp32 -> bf16
            int f = t + i * 256;
            int row = f >> 4, c4 = (f & 15) << 2;
            float4 v = *reinterpret_cast<const float4*>(ps + (size_t)(m0 + row) * XDIM + kt + c4);
            ushort4 o; o.x = f2bf(v.x); o.y = f2bf(v.y); o.z = f2bf(v.z); o.w = f2bf(v.w);
            *reinterpret_cast<ushort4*>(&shA[row * LDS_STRIDE + c4]) = o;
        }
        #pragma unroll
        for (int i = 0; i < 4; i++) {               // B: 128x64 bf16
            int g = t + i * 256;
            int row = g >> 3, c8 = (g & 7) << 3;
            *reinterpret_cast<uint4*>(&shB[row * LDS_STRIDE + c8]) =
                *reinterpret_cast<const uint4*>(w1t + (size_t)(n0 + row) * HDIM + kt + c8);
        }
        __syncthreads();
        #pragma unroll
        for (int ks = 0; ks < BK; ks += 32) {
            bf16x8 af[4], bfr[4];
            #pragma unroll
            for (int i = 0; i < 4; i++)
                af[i] = *reinterpret_cast<const bf16x8*>(&shA[(mbase + i * 16 + lrow) * LDS_STRIDE + ks + lq * 8]);
            #pragma unroll
            for (int j = 0; j < 4; j++)
                bfr[j] = *reinterpret_cast<const bf16x8*>(&shB[(nbase + j * 16 + lrow) * LDS_STRIDE + ks + lq * 8]);
            #pragma unroll
            for (int i = 0; i < 4; i++)
                #pragma unroll
                for (int j = 0; j < 4; j++)
                    acc[i][j] = __builtin_amdgcn_mfma_f32_16x16x32_bf16(af[i], bfr[j], acc[i][j], 0, 0, 0);
        }
        __syncthreads();
    }

    #pragma unroll
    for (int i = 0; i < 4; i++) {
        #pragma unroll
        for (int r = 0; r < 4; r++) {
            int gm = m0 + mbase + i * 16 + lq * 4 + r;
            int sg = segids[gm];
            const float* sb = segbias + (size_t)sg * HDIM;
            #pragma unroll
            for (int j = 0; j < 4; j++) {
                int gn = n0 + nbase + j * 16 + lrow;       // C/D: col = lane&15, row = (lane>>4)*4+r
                float v = acc[i][j][r] + sb[gn] + b1[gn];
                v = v > 0.f ? v : 0.f;
                h1[(size_t)gm * HDIM + gn] = f2bf(v);
            }
        }
    }
}

// ---------------- GEMM2 fused: logits += relu(h1 @ W2 + b2) . W3   (h2 never materialized; b3 cancels in softmax)
__global__ __launch_bounds__(256) void gemm2_kernel(const unsigned short* __restrict__ h1,
                                                    const unsigned short* __restrict__ w2t,
                                                    const float* __restrict__ b2,
                                                    const float* __restrict__ w3,
                                                    float* __restrict__ logits) {
    __shared__ unsigned short shA[TM * LDS_STRIDE];
    __shared__ unsigned short shB[TN * LDS_STRIDE];

    const int bid = blockIdx.x;
    const int m0 = (bid >> 2) * TM;
    const int n0 = (bid & 3) * TN;
    const int t = threadIdx.x;
    const int w = t >> 6, L = t & 63;
    const int mbase = (w >> 1) * 64, nbase = (w & 1) * 64;
    const int lrow = L & 15, lq = L >> 4;

    f32x4 acc[4][4] = {};

    for (int kt = 0; kt < HDIM; kt += BK) {
        #pragma unroll
        for (int i = 0; i < 4; i++) {
            int g = t + i * 256;
            int row = g >> 3, c8 = (g & 7) << 3;
            *reinterpret_cast<uint4*>(&shA[row * LDS_STRIDE + c8]) =
                *reinterpret_cast<const uint4*>(h1 + (size_t)(m0 + row) * HDIM + kt + c8);
        }
        #pragma unroll
        for (int i = 0; i < 4; i++) {
            int g = t + i * 256;
            int row = g >> 3, c8 = (g & 7) << 3;
            *reinterpret_cast<uint4*>(&shB[row * LDS_STRIDE + c8]) =
                *reinterpret_cast<const uint4*>(w2t + (size_t)(n0 + row) * HDIM + kt + c8);
        }
        __syncthreads();
        #pragma unroll
        for (int ks = 0; ks < BK; ks += 32) {
            bf16x8 af[4], bfr[4];
            #pragma unroll
            for (int i = 0; i < 4; i++)
                af[i] = *reinterpret_cast<const bf16x8*>(&shA[(mbase + i * 16 + lrow) * LDS_STRIDE + ks + lq * 8]);
            #pragma unroll
            for (int j = 0; j < 4; j++)
                bfr[j] = *reinterpret_cast<const bf16x8*>(&shB[(nbase + j * 16 + lrow) * LDS_STRIDE + ks + lq * 8]);
            #pragma unroll
            for (int i = 0; i < 4; i++)
                #pragma unroll
                for (int j = 0; j < 4; j++)
                    acc[i][j] = __builtin_amdgcn_mfma_f32_16x16x32_bf16(af[i], bfr[j], acc[i][j], 0, 0, 0);
        }
        __syncthreads();
    }

    float w3v[4], b2v[4];
    #pragma unroll
    for (int j = 0; j < 4; j++) {
        int gn = n0 + nbase + j * 16 + lrow;
        w3v[j] = w3[gn];
        b2v[j] = b2[gn];
    }
    #pragma unroll
    for (int i = 0; i < 4; i++) {
        #pragma unroll
        for (int r = 0; r < 4; r++) {
            float p = 0.f;
            #pragma unroll
            for (int j = 0; j < 4; j++) {
                float h2 = acc[i][j][r] + b2v[j];
                h2 = h2 > 0.f ? h2 : 0.f;
                p += h2 * w3v[j];
            }
            p += __shfl_xor(p, 1, 64);   // reduce over the 16 cols held by lrow
            p += __shfl_xor(p, 2, 64);
            p += __shfl_xor(p, 4, 64);
            p += __shfl_xor(p, 8, 64);
            if (lrow == 0)
                atomicAdd(&logits[m0 + mbase + i * 16 + lq * 4 + r], p);
        }
    }
}

// ---------------- per-segment softmax stats (segments are contiguous: binary search bounds)
__global__ __launch_bounds__(256) void stats_kernel(const float* __restrict__ logits,
                                                    const int* __restrict__ segids,
                                                    float* __restrict__ stats) {
    const int b = blockIdx.x;
    const int t = threadIdx.x;
    __shared__ float sred[4];
    const int start = lower_bound_seg(segids, T_TOK, b);
    const int end   = lower_bound_seg(segids, T_TOK, b + 1);
    float m = -3.4e38f;
    for (int i = start + t; i < end; i += 256) m = fmaxf(m, logits[i]);
    for (int d = 32; d; d >>= 1) m = fmaxf(m, __shfl_down(m, d, 64));
    if ((t & 63) == 0) sred[t >> 6] = m;
    __syncthreads();
    m = fmaxf(fmaxf(sred[0], sred[1]), fmaxf(sred[2], sred[3]));
    __syncthreads();
    float s = 0.f;
    for (int i = start + t; i < end; i += 256) s += __expf(logits[i] - m);
    for (int d = 32; d; d >>= 1) s += __shfl_down(s, d, 64);
    if ((t & 63) == 0) sred[t >> 6] = s;
    __syncthreads();
    if (t == 0) { stats[2 * b] = m; stats[2 * b + 1] = sred[0] + sred[1] + sred[2] + sred[3]; }
}

// ---------------- pooled[b][c] += sum_t softmax_w[t] * ps[t][c]   (8-way token split per segment)
__global__ __launch_bounds__(512) void pool_kernel(const float* __restrict__ ps,
                                                   const float* __restrict__ logits,
                                                   const int* __restrict__ segids,
                                                   const float* __restrict__ stats,
                                                   float* __restrict__ pooled) {
    const int s = blockIdx.x;       // 0..7 split
    const int b = blockIdx.y;
    const int t = threadIdx.x;      // feature
    __shared__ float wv[512];
    const int start = lower_bound_seg(segids, T_TOK, b);
    const int end   = lower_bound_seg(segids, T_TOK, b + 1);
    const int n = end - start;
    const int per = (n + 7) >> 3;
    const int s0 = start + s * per;
    const int s1 = min(s0 + per, end);
    const float m = stats[2 * b];
    const float inv = 1.f / stats[2 * b + 1];
    float acc = 0.f;
    for (int base = s0; base < s1; base += 512) {
        int cnt = min(512, s1 - base);
        __syncthreads();
        if (t < cnt) wv[t] = __expf(logits[base + t] - m) * inv;
        __syncthreads();
        for (int i = 0; i < cnt; i++)
            acc += wv[i] * ps[(size_t)(base + i) * XDIM + t];
    }
    atomicAdd(&pooled[b * XDIM + t], acc);
}

// ---------------- final_fc: out = relu(pooled @ Wf1 + bf1) @ Wf2 + bf2
__global__ __launch_bounds__(512) void final_kernel(const float* __restrict__ pooled,
                                                    const float* __restrict__ wf1,
                                                    const float* __restrict__ bf1,
                                                    const float* __restrict__ wf2,
                                                    const float* __restrict__ bf2,
                                                    float* __restrict__ out) {
    const int b = blockIdx.x;
    const int t = threadIdx.x;
    __shared__ float sp[512];
    __shared__ float r0s[8], r1s[8];
    sp[t] = pooled[b * XDIM + t];
    __syncthreads();
    float acc = bf1[t];
    #pragma unroll 4
    for (int k = 0; k < 512; k++) acc += sp[k] * wf1[(size_t)k * 512 + t];
    float h = fmaxf(acc, 0.f);
    float p0 = h * wf2[t * 2 + 0];
    float p1 = h * wf2[t * 2 + 1];
    for (int d = 32; d; d >>= 1) { p0 += __shfl_down(p0, d, 64); p1 += __shfl_down(p1, d, 64); }
    if ((t & 63) == 0) { r0s[t >> 6] = p0; r1s[t >> 6] = p1; }
    __syncthreads();
    if (t == 0) {
        float a = 0.f, c = 0.f;
        #pragma unroll
        for (int i = 0; i < 8; i++) { a += r0s[i]; c += r1s[i]; }
        out[b * 2 + 0] = a + bf2[0];
        out[b * 2 + 1] = c + bf2[1];
    }
}

extern "C" void kernel_launch(void* const* d_in, const int* in_sizes, int n_in,
                              void* d_out, int out_size, void* d_ws, size_t ws_size,
                              hipStream_t stream) {
    const float* ps  = (const float*)d_in[0];
    const float* io  = (const float*)d_in[1];
    const int*   seg = (const int*)d_in[2];
    const float* W1  = (const float*)d_in[3];
    const float* b1  = (const float*)d_in[4];
    const float* W2  = (const float*)d_in[5];
    const float* b2  = (const float*)d_in[6];
    const float* W3  = (const float*)d_in[7];
    // d_in[8] = b3: shift-invariant under segment softmax -> unused
    const float* Wf1 = (const float*)d_in[9];
    const float* bf1 = (const float*)d_in[10];
    const float* Wf2 = (const float*)d_in[11];
    const float* bf2 = (const float*)d_in[12];
    float* out = (float*)d_out;

    char* ws = (char*)d_ws;
    float*          segbias = (float*)(ws + 0);              // 64*512*4   = 131072
    float*          logits  = (float*)(ws + 131072);         // 65536*4    = 262144
    float*          stats   = (float*)(ws + 393216);         // 128*4 (pad to 4096)
    float*          pooled  = (float*)(ws + 397312);         // 64*512*4   = 131072
    unsigned short* w1t     = (unsigned short*)(ws + 528384);   // 512*512*2
    unsigned short* w2t     = (unsigned short*)(ws + 1052672);  // 512*512*2
    unsigned short* h1      = (unsigned short*)(ws + 1576960);  // 65536*512*2 = 64 MiB

    hipMemsetAsync(ws, 0, 393216, stream);            // segbias + logits
    hipMemsetAsync(ws + 397312, 0, 131072, stream);   // pooled

    transpose_to_bf16<<<1024, 256, 0, stream>>>(W1, w1t);   // W1 upper 512 rows
    transpose_to_bf16<<<1024, 256, 0, stream>>>(W2, w2t);
    segbias_kernel<<<dim3(4, 64), 512, 0, stream>>>(io, W1, segbias);
    gemm1_kernel<<<2048, 256, 0, stream>>>(ps, w1t, segbias, b1, seg, h1);
    gemm2_kernel<<<2048, 256, 0, stream>>>(h1, w2t, b2, W3, logits);
    stats_kernel<<<64, 256, 0, stream>>>(logits, seg, stats);
    pool_kernel<<<dim3(8, 64), 512, 0, stream>>>(ps, logits, seg, stats, pooled);
    final_kernel<<<64, 512, 0, stream>>>(pooled, Wf1, bf1, Wf2, bf2, out);
}